// Round 5
// baseline (403.753 us; speedup 1.0000x reference)
//
#include <hip/hip_runtime.h>
#include <math.h>

typedef unsigned short u16;
typedef __bf16 bf16x8 __attribute__((ext_vector_type(8)));
typedef float f32x4 __attribute__((ext_vector_type(4)));

union B8u { uint4 u; bf16x8 v; u16 s[8]; };

__device__ __forceinline__ u16 f2bf(float f){
  unsigned u = __float_as_uint(f);
  u += 0x7fffu + ((u >> 16) & 1u);   // RNE
  return (u16)(u >> 16);
}
__device__ __forceinline__ u16 f2bf_fast(float f){ // round-half-up (P values >=0)
  return (u16)((__float_as_uint(f) + 0x8000u) >> 16);
}
__device__ __forceinline__ bf16x8 ld8(const u16* p){
  B8u x; x.u = *(const uint4*)p; return x.v;
}
// async global->LDS, 16B per lane; lds base must be wave-uniform, lane i lands
// at lds + i*16 (m97/m104 semantics).
__device__ __forceinline__ void glds16(const u16* g, u16* l){
  __builtin_amdgcn_global_load_lds(
      (const __attribute__((address_space(1))) void*)g,
      (__attribute__((address_space(3))) void*)l, 16, 0, 0);
}

// ---------------- weight transpose-cast: W[k][n] fp32 -> Wt[n][k] bf16 -----
__global__ void wcast_k(const float* __restrict__ Wq, const float* __restrict__ Wk,
                        const float* __restrict__ Wv, const float* __restrict__ Wo,
                        u16* __restrict__ Tq, u16* __restrict__ Tk,
                        u16* __restrict__ Tv, u16* __restrict__ To){
  const float* W; u16* T;
  switch(blockIdx.z){
    case 0: W = Wq; T = Tq; break;
    case 1: W = Wk; T = Tk; break;
    case 2: W = Wv; T = Tv; break;
    default: W = Wo; T = To; break;
  }
  __shared__ u16 tile[32][33];
  int tx = threadIdx.x & 31, ty = threadIdx.x >> 5;   // 32 x 8
  int n0 = blockIdx.x * 32, k0 = blockIdx.y * 32;
  for(int i = ty; i < 32; i += 8)
    tile[i][tx] = f2bf(W[(size_t)(k0 + i) * 1024 + n0 + tx]);
  __syncthreads();
  for(int i = ty; i < 32; i += 8)
    T[(size_t)(n0 + i) * 1024 + k0 + tx] = tile[tx][i];
}

// ---------------- row LayerNorm (D=1024) + bf16 cast --------------------
__device__ __forceinline__ void ln_core(const float* __restrict__ X,
                                        u16* __restrict__ Y, float* __restrict__ Yf,
                                        const float* __restrict__ g,
                                        const float* __restrict__ bb,
                                        int doLN, int row, int t, float* red){
  float4 v = ((const float4*)(X + (size_t)row * 1024))[t];
  float o0 = v.x, o1 = v.y, o2 = v.z, o3 = v.w;
  if(doLN){
    float s  = o0 + o1 + o2 + o3;
    float ss = o0*o0 + o1*o1 + o2*o2 + o3*o3;
    for(int o = 32; o > 0; o >>= 1){
      s  += __shfl_down(s,  o, 64);
      ss += __shfl_down(ss, o, 64);
    }
    if((t & 63) == 0){ red[t >> 6] = s; red[4 + (t >> 6)] = ss; }
    __syncthreads();
    s  = red[0] + red[1] + red[2] + red[3];
    ss = red[4] + red[5] + red[6] + red[7];
    float mu  = s * (1.f/1024.f);
    float var = ss * (1.f/1024.f) - mu*mu;
    float rs  = rsqrtf(var + 1e-5f);
    float4 gg = ((const float4*)g)[t];
    float4 bv = ((const float4*)bb)[t];
    o0 = (o0 - mu) * rs * gg.x + bv.x;
    o1 = (o1 - mu) * rs * gg.y + bv.y;
    o2 = (o2 - mu) * rs * gg.z + bv.z;
    o3 = (o3 - mu) * rs * gg.w + bv.w;
  }
  if(Yf){
    float4 w; w.x=o0; w.y=o1; w.z=o2; w.w=o3;
    ((float4*)(Yf + (size_t)row * 1024))[t] = w;
  }
  ushort4 u;
  u.x = f2bf(o0); u.y = f2bf(o1); u.z = f2bf(o2); u.w = f2bf(o3);
  ((ushort4*)(Y + (size_t)row * 1024))[t] = u;
}

// fused: z=0 Q->QN (LN), z=1 K->KN (LN), z=2 V->VB (cast only)
__global__ void ln3_cast(const float* __restrict__ Q, const float* __restrict__ K,
                         const float* __restrict__ V,
                         u16* __restrict__ QN, u16* __restrict__ KN, u16* __restrict__ VB,
                         const float* __restrict__ g, const float* __restrict__ bb){
  __shared__ float red[8];
  const float* X; u16* Y; int doLN = 1;
  switch(blockIdx.y){
    case 0: X = Q; Y = QN; break;
    case 1: X = K; Y = KN; break;
    default: X = V; Y = VB; doLN = 0; break;
  }
  ln_core(X, Y, nullptr, g, bb, doLN, blockIdx.x, threadIdx.x, red);
}

__global__ void ln_post(const float* __restrict__ X, u16* __restrict__ Y,
                        float* __restrict__ Yf,
                        const float* __restrict__ g, const float* __restrict__ bb){
  __shared__ float red[8];
  ln_core(X, Y, Yf, g, bb, 1, blockIdx.x, threadIdx.x, red);
}

// ---------------- bf16 GEMM core, B^T layout ------------------------------
// C[m][n] = sum_k A[m][k]*Bt[n][k]; 128x128 tile, 4 waves 2x2 of 64x64, BK=64.
// MODE 0: write bf16 C*oscale.  MODE 1: out = Resid + gelu_exact(C), fp32.
template<int MODE>
__device__ __forceinline__ void gemm_core(
  const u16* __restrict__ A, const u16* __restrict__ Bt,
  u16* __restrict__ Obf, float* __restrict__ Of32, const float* __restrict__ Resid,
  int m0, int n0, int ldC, float oscale, u16* as, u16* bs)
{
  const int K = 1024;
  int t = threadIdx.x;
  int wave = t >> 6, lane = t & 63, quad = lane >> 4, l16 = lane & 15;
  int wm = (wave >> 1) * 64, wn = (wave & 1) * 64;
  int srow = t >> 3;              // wave*8 + lane/8
  f32x4 acc[4][4] = {};
  for(int k0 = 0; k0 < K; k0 += 64){
    __syncthreads();              // all waves done reading previous tile
    for(int p = 0; p < 4; p++){
      int r = p*32 + srow;
      int c = (t & 7) ^ (r & 7);
      glds16(A  + (size_t)(m0 + r) * K + k0 + c*8, as + p*2048 + wave*512);
      glds16(Bt + (size_t)(n0 + r) * K + k0 + c*8, bs + p*2048 + wave*512);
    }
    __syncthreads();              // drains vmcnt: tile staged
    bf16x8 af[2][4], bfr[2][4];
    for(int kk = 0; kk < 2; kk++)
      for(int mt = 0; mt < 4; mt++){
        int ra = wm + mt*16 + l16;
        af[kk][mt]  = ld8(&as[ra*64 + (((kk*4 + quad) ^ (ra & 7)) * 8)]);
        int rb = wn + mt*16 + l16;
        bfr[kk][mt] = ld8(&bs[rb*64 + (((kk*4 + quad) ^ (rb & 7)) * 8)]);
      }
    for(int kk = 0; kk < 2; kk++)
      for(int mt = 0; mt < 4; mt++)
        for(int nt = 0; nt < 4; nt++)
          acc[mt][nt] = __builtin_amdgcn_mfma_f32_16x16x32_bf16(af[kk][mt], bfr[kk][nt], acc[mt][nt], 0, 0, 0);
  }
  for(int mt = 0; mt < 4; mt++)
    for(int nt = 0; nt < 4; nt++){
      int col = n0 + wn + nt*16 + l16;
      for(int r = 0; r < 4; r++){
        int row = m0 + wm + mt*16 + quad*4 + r;
        size_t idx = (size_t)row * ldC + col;
        float v = acc[mt][nt][r];
        if(MODE == 0){
          Obf[idx] = f2bf(v * oscale);
        } else {
          float ge = 0.5f * v * (1.0f + erff(v * 0.70710678118f));
          Of32[idx] = Resid[idx] + ge;
        }
      }
    }
}

// fused Q/K/V projections: 1536 blocks.
// XCD-chunked remap (bijective: bx = 8t+c -> w = t + 192c): each XCD gets 192
// contiguous work items ordered (z, m, n) with n fastest, so the 8 n-tiles
// sharing one 256KB A-panel colocate on a single XCD's L2.
__global__ __launch_bounds__(256,3) void qkv_gemm(
  const u16* __restrict__ QN, const u16* __restrict__ KN, const u16* __restrict__ VB,
  const u16* __restrict__ WTq, const u16* __restrict__ WTk, const u16* __restrict__ WTv,
  u16* __restrict__ QP, u16* __restrict__ KP, u16* __restrict__ VT, float qscale)
{
  __shared__ u16 as[128*64];
  __shared__ u16 bs[128*64];
  int bx = blockIdx.x;
  int w = (bx >> 3) + 192 * (bx & 7);   // XCD-chunked work index, [0,1536)
  int z = w / 512, id = w - z * 512;    // id in [0,512): m = id>>3, n = id&7
  if(z == 0){
    gemm_core<0>(QN, WTq, QP, nullptr, nullptr, (id >> 3)*128, (id & 7)*128, 1024, qscale, as, bs);
  } else if(z == 1){
    gemm_core<0>(KN, WTk, KP, nullptr, nullptr, (id >> 3)*128, (id & 7)*128, 1024, 1.0f, as, bs);
  } else {
    gemm_core<0>(WTv, VB, VT, nullptr, nullptr, (id & 7)*128, (id >> 3)*128, 8192, 1.0f, as, bs);
  }
}

// final: Out = OLN + gelu(OLNb x WTo)
__global__ __launch_bounds__(256,3) void out_gemm(
  const u16* __restrict__ A, const u16* __restrict__ Bt,
  float* __restrict__ Of32, const float* __restrict__ Resid)
{
  __shared__ u16 as[128*64];
  __shared__ u16 bs[128*64];
  gemm_core<1>(A, Bt, nullptr, Of32, Resid, blockIdx.x*128, blockIdx.y*128, 1024, 1.0f, as, bs);
}

// ---------------- flash attention: 128 q-rows/block, Tk=64, HD=128 ---------
// R5: WAVE-PAIRING to halve LDS B-fragment traffic (the measured wall:
// ~650 KB LDS data/CU-iter ~= 5800 cyc at 112 B/cyc/CU ~= 90% of the 6400-cyc
// wall; MFMA only 39%). Waves w and w+4 own the SAME 32 q-rows (2 m-tiles,
// wq=(w&3)*32) but each handles HALF the 64 tokens (khalf=w>>2). Every
// ks/vts fragment read now feeds 2 MFMAs (shared across m-tiles): per-wave
// 8+8 B-reads for 32 MFMAs (was 16+16). LDS/CU-iter ~390 KB (-40%).
// Cost: oacc & l are partial (per khalf) -> one LDS pair-reduction in the
// epilogue (o_lds[128][132]+l_lds reuse the 80KB after the final barrier).
// dbuf ks/vts, single barrier/step (R4 structure), incremental per-lane
// staging pointers to hold VGPR near the 128 bound (4 waves/SIMD).
__global__ __launch_bounds__(512,4) void flash_k(
  const u16* __restrict__ Qp, const u16* __restrict__ Kp, const u16* __restrict__ VT,
  float* __restrict__ Oout)
{
  __shared__ __align__(16) u16 smem[40960];   // 80 KB total
  u16* ks  = smem;            // [2][64][128] dbuf: chunk c at c^(row&15)
  u16* vts = smem + 16384;    // [2][128][64] dbuf: chunk c at c^(row&7)
  u16* ps  = smem + 32768;    // [128][64]: chunk c at c^(row&7)
  int t = threadIdx.x, wave = t >> 6, lane = t & 63, quad = lane >> 4, l16 = lane & 15;
  int l = blockIdx.x;            // 512 blocks
  int xcd = l & 7, i = l >> 3;   // i in 0..63
  int bh = xcd + 8 * (i & 3);    // 4 heads per XCD -> 4MB L2 working set
  int qt = i >> 2;               // 0..15 (128-row q tiles)
  int b = bh >> 3, h = bh & 7;
  size_t rowbase = (size_t)b * 2048;
  int colbase = h * 128;
  int wq = (wave & 3) * 32;      // this wave's q-row offset (2 m-tiles)
  int kb = (wave >> 2) * 32;     // this wave's token half within the 64-tile
  int khq = (kb >> 3) + quad;    // chunk index for pa/vts reads (khalf*4+quad)

  // Q fragments to registers: 32 wave-private rows, 2 m-tiles
  bf16x8 aq[2][4];
  for(int m = 0; m < 2; m++){
    const u16* qrow = Qp + (rowbase + qt*128 + wq + m*16 + l16) * 1024 + colbase + quad*8;
    for(int kk = 0; kk < 4; kk++) aq[m][kk] = ld8(qrow + kk*32);
  }

  float l_i[2][4] = {};          // per-lane, per-khalf partial denominators
  f32x4 oacc[2][8] = {};         // per-khalf partial O

  int krow = t >> 4;             // 0..31
  int kchunk = t & 15;
  int vrow = t >> 3;             // 0..63
  int vchunk = t & 7;

  // per-lane global source pointers; advance by constants each staged step.
  // second half-tile is a constant offset: K +32 rows (=32768 u16, same xor
  // since (32+krow)&15==krow&15); V +64 rows (=524288 u16, (64+vrow)&7 same).
  const u16* kp = Kp + (rowbase + krow) * 1024 + colbase + (kchunk ^ (krow & 15)) * 8;
  const u16* vt = VT + (size_t)(colbase + vrow) * 8192 + rowbase + (vchunk ^ (vrow & 7)) * 8;

  // prologue: stage tile 0 into buf 0
  {
    u16* kd = ks + wave*512;
    u16* vd = vts + wave*512;
    glds16(kp, kd);          glds16(kp + 32768, kd + 4096);
    glds16(vt, vd);          glds16(vt + 524288, vd + 4096);
    kp += 65536; vt += 64;
  }
  __syncthreads();               // vmcnt(0): tile 0 staged

  for(int kt = 0; kt < 2048; kt += 64){
    int buf = (kt >> 6) & 1;
    const u16* ksc = ks + buf*8192;
    const u16* vtc = vts + buf*8192;
    // stage next tile into buf^1 (readers retired by last barrier; drained
    // by this step's end barrier -> covered by the whole step's compute)
    if(kt + 64 < 2048){
      u16* kd = ks + (buf^1)*8192 + wave*512;
      u16* vd = vts + (buf^1)*8192 + wave*512;
      glds16(kp, kd);          glds16(kp + 32768, kd + 4096);
      glds16(vt, vd);          glds16(vt + 524288, vd + 4096);
      kp += 65536; vt += 64;
    }
    // ---- S = q k^T for this wave's 32 rows x 32 token-cols, ct-chunked to
    //      keep only 8 s-regs live (VGPR budget)
    for(int ct = 0; ct < 2; ct++){
      f32x4 s0 = {}, s1 = {};
      __builtin_amdgcn_s_setprio(1);
      for(int kk = 0; kk < 4; kk++){
        bf16x8 bb = ld8(&ksc[(kb + ct*16 + l16)*128 + (((kk*4 + quad) ^ l16) * 8)]);
        s0 = __builtin_amdgcn_mfma_f32_16x16x32_bf16(aq[0][kk], bb, s0, 0, 0, 0);
        s1 = __builtin_amdgcn_mfma_f32_16x16x32_bf16(aq[1][kk], bb, s1, 0, 0, 0);
      }
      __builtin_amdgcn_s_setprio(0);
      for(int r = 0; r < 4; r++){
        s0[r] = __builtin_amdgcn_exp2f(s0[r]);
        s1[r] = __builtin_amdgcn_exp2f(s1[r]);
      }
      int ch = (kb >> 3) + ct*2 + (l16 >> 3);   // source chunk of this col
      for(int r = 0; r < 4; r++){
        l_i[0][r] += s0[r];
        l_i[1][r] += s1[r];
        int pr0 = wq + quad*4 + r;              // m=0 row
        int pr1 = pr0 + 16;                     // m=1 row (same &7)
        int cx = (ch ^ (pr0 & 7)) * 8 + (l16 & 7);
        ps[pr0*64 + cx] = f2bf_fast(s0[r]);
        ps[pr1*64 + cx] = f2bf_fast(s1[r]);
      }
    }
    // ---- O += P V  (this wave's token half; frags shared across 2 m-tiles)
    bf16x8 pa0 = ld8(&ps[(wq + l16)*64      + ((khq ^ (l16 & 7)) * 8)]);
    bf16x8 pa1 = ld8(&ps[(wq + 16 + l16)*64 + ((khq ^ (l16 & 7)) * 8)]);
    __builtin_amdgcn_s_setprio(1);
    for(int dt = 0; dt < 8; dt++){
      bf16x8 bb = ld8(&vtc[(dt*16 + l16)*64 + ((khq ^ (l16 & 7)) * 8)]);
      oacc[0][dt] = __builtin_amdgcn_mfma_f32_16x16x32_bf16(pa0, bb, oacc[0][dt], 0, 0, 0);
      oacc[1][dt] = __builtin_amdgcn_mfma_f32_16x16x32_bf16(pa1, bb, oacc[1][dt], 0, 0, 0);
    }
    __builtin_amdgcn_s_setprio(0);
    // single barrier: drains this step's DMAs; retires all buf[cur] readers
    __syncthreads();
  }

  // ---- pair-reduction epilogue: khalf 0 publishes, khalf 1 adds & writes.
  // Reuses smem (all ks/vts/ps reads retired by the loop's final barrier).
  float* o_lds = (float*)smem;                 // [128][132] padded f32
  float* l_lds = (float*)(smem + 33792);       // byte 67584: [128][16] f32
  if(kb == 0){
    for(int m = 0; m < 2; m++)
      for(int r = 0; r < 4; r++){
        int row = wq + m*16 + quad*4 + r;
        l_lds[row*16 + l16] = l_i[m][r];
        for(int dt = 0; dt < 8; dt++)
          o_lds[row*132 + dt*16 + l16] = oacc[m][dt][r];
      }
  }
  __syncthreads();
  if(kb != 0){
    for(int m = 0; m < 2; m++){
      float rinv[4];
      for(int r = 0; r < 4; r++){
        int row = wq + m*16 + quad*4 + r;
        float lv = l_i[m][r] + l_lds[row*16 + l16];
        for(int o = 1; o < 16; o <<= 1) lv += __shfl_xor(lv, o, 64);
        rinv[r] = 1.f / lv;
      }
      for(int dt = 0; dt < 8; dt++){
        int col = colbase + dt*16 + l16;
        for(int r = 0; r < 4; r++){
          int row = wq + m*16 + quad*4 + r;
          size_t grow = rowbase + qt*128 + row;
          Oout[grow * 1024 + col] = (oacc[m][dt][r] + o_lds[row*132 + dt*16 + l16]) * rinv[r];
        }
      }
    }
  }
}

// ---------------------------------------------------------------------------
extern "C" void kernel_launch(void* const* d_in, const int* in_sizes, int n_in,
                              void* d_out, int out_size, void* d_ws, size_t ws_size,
                              hipStream_t stream){
  (void)in_sizes; (void)n_in; (void)out_size; (void)ws_size;
  const float* Q    = (const float*)d_in[0];
  const float* K    = (const float*)d_in[1];
  const float* V    = (const float*)d_in[2];
  const float* Wq   = (const float*)d_in[3];
  const float* Wk   = (const float*)d_in[4];
  const float* Wv   = (const float*)d_in[5];
  const float* Wo   = (const float*)d_in[6];
  const float* pre_g = (const float*)d_in[7];
  const float* pre_b = (const float*)d_in[8];
  const float* ln_g  = (const float*)d_in[9];
  const float* ln_b  = (const float*)d_in[10];
  float* Out = (float*)d_out;
  char* ws = (char*)d_ws;
  const size_t MB = 1024 * 1024;
  // ws layout (peak 104 MB):
  u16* WTq = (u16*)(ws + 0*MB);    // 2MB each, transposed bf16 weights
  u16* WTk = (u16*)(ws + 2*MB);
  u16* WTv = (u16*)(ws + 4*MB);
  u16* WTo = (u16*)(ws + 6*MB);
  u16* QN  = (u16*)(ws + 8*MB);    // 16MB each: LN'd/cast inputs
  u16* KN  = (u16*)(ws + 24*MB);
  u16* VB  = (u16*)(ws + 40*MB);
  u16* QP  = (u16*)(ws + 56*MB);   // 16MB each: projections
  u16* KP  = (u16*)(ws + 72*MB);
  u16* VT  = (u16*)(ws + 88*MB);   // 16MB: V projection TRANSPOSED [1024][8192]
  float* OLN  = (float*)(ws + 8*MB);   // 32MB, reuses QN/KN after flash
  u16*   OLNb = (u16*)(ws + 40*MB);    // 16MB, reuses VB

  const float qscale = 0.03125f * 1.44269504089f;  // 1/TEMP * log2(e)

  wcast_k<<<dim3(32,32,4), 256, 0, stream>>>(Wq,Wk,Wv,Wo, WTq,WTk,WTv,WTo);
  ln3_cast<<<dim3(8192,3), 256, 0, stream>>>(Q, K, V, QN, KN, VB, pre_g, pre_b);
  qkv_gemm<<<1536, 256, 0, stream>>>(QN, KN, VB, WTq, WTk, WTv, QP, KP, VT, qscale);
  flash_k<<<512, 512, 0, stream>>>(QP, KP, VT, Out);
  ln_post<<<8192, 256, 0, stream>>>(Out, OLNb, OLN, ln_g, ln_b);
  out_gemm<<<dim3(64,8), 256, 0, stream>>>(OLNb, WTo, Out, OLN);
}

// Round 6
// 365.472 us; speedup vs baseline: 1.1047x; 1.1047x over previous
//
#include <hip/hip_runtime.h>
#include <math.h>

typedef unsigned short u16;
typedef __bf16 bf16x8 __attribute__((ext_vector_type(8)));
typedef float f32x4 __attribute__((ext_vector_type(4)));

union B8u { uint4 u; bf16x8 v; u16 s[8]; };

__device__ __forceinline__ u16 f2bf(float f){
  unsigned u = __float_as_uint(f);
  u += 0x7fffu + ((u >> 16) & 1u);   // RNE
  return (u16)(u >> 16);
}
__device__ __forceinline__ u16 f2bf_fast(float f){ // round-half-up (P values >=0)
  return (u16)((__float_as_uint(f) + 0x8000u) >> 16);
}
__device__ __forceinline__ bf16x8 ld8(const u16* p){
  B8u x; x.u = *(const uint4*)p; return x.v;
}
// async global->LDS, 16B per lane; lds base must be wave-uniform, lane i lands
// at lds + i*16 (m97/m104 semantics).
__device__ __forceinline__ void glds16(const u16* g, u16* l){
  __builtin_amdgcn_global_load_lds(
      (const __attribute__((address_space(1))) void*)g,
      (__attribute__((address_space(3))) void*)l, 16, 0, 0);
}

// ---------------- weight transpose-cast: W[k][n] fp32 -> Wt[n][k] bf16 -----
__global__ void wcast_k(const float* __restrict__ Wq, const float* __restrict__ Wk,
                        const float* __restrict__ Wv, const float* __restrict__ Wo,
                        u16* __restrict__ Tq, u16* __restrict__ Tk,
                        u16* __restrict__ Tv, u16* __restrict__ To){
  const float* W; u16* T;
  switch(blockIdx.z){
    case 0: W = Wq; T = Tq; break;
    case 1: W = Wk; T = Tk; break;
    case 2: W = Wv; T = Tv; break;
    default: W = Wo; T = To; break;
  }
  __shared__ u16 tile[32][33];
  int tx = threadIdx.x & 31, ty = threadIdx.x >> 5;   // 32 x 8
  int n0 = blockIdx.x * 32, k0 = blockIdx.y * 32;
  for(int i = ty; i < 32; i += 8)
    tile[i][tx] = f2bf(W[(size_t)(k0 + i) * 1024 + n0 + tx]);
  __syncthreads();
  for(int i = ty; i < 32; i += 8)
    T[(size_t)(n0 + i) * 1024 + k0 + tx] = tile[tx][i];
}

// ---------------- row LayerNorm (D=1024) + bf16 cast --------------------
__device__ __forceinline__ void ln_core(const float* __restrict__ X,
                                        u16* __restrict__ Y, float* __restrict__ Yf,
                                        const float* __restrict__ g,
                                        const float* __restrict__ bb,
                                        int doLN, int row, int t, float* red){
  float4 v = ((const float4*)(X + (size_t)row * 1024))[t];
  float o0 = v.x, o1 = v.y, o2 = v.z, o3 = v.w;
  if(doLN){
    float s  = o0 + o1 + o2 + o3;
    float ss = o0*o0 + o1*o1 + o2*o2 + o3*o3;
    for(int o = 32; o > 0; o >>= 1){
      s  += __shfl_down(s,  o, 64);
      ss += __shfl_down(ss, o, 64);
    }
    if((t & 63) == 0){ red[t >> 6] = s; red[4 + (t >> 6)] = ss; }
    __syncthreads();
    s  = red[0] + red[1] + red[2] + red[3];
    ss = red[4] + red[5] + red[6] + red[7];
    float mu  = s * (1.f/1024.f);
    float var = ss * (1.f/1024.f) - mu*mu;
    float rs  = rsqrtf(var + 1e-5f);
    float4 gg = ((const float4*)g)[t];
    float4 bv = ((const float4*)bb)[t];
    o0 = (o0 - mu) * rs * gg.x + bv.x;
    o1 = (o1 - mu) * rs * gg.y + bv.y;
    o2 = (o2 - mu) * rs * gg.z + bv.z;
    o3 = (o3 - mu) * rs * gg.w + bv.w;
  }
  if(Yf){
    float4 w; w.x=o0; w.y=o1; w.z=o2; w.w=o3;
    ((float4*)(Yf + (size_t)row * 1024))[t] = w;
  }
  ushort4 u;
  u.x = f2bf(o0); u.y = f2bf(o1); u.z = f2bf(o2); u.w = f2bf(o3);
  ((ushort4*)(Y + (size_t)row * 1024))[t] = u;
}

// fused: z=0 Q->QN (LN), z=1 K->KN (LN), z=2 V->VB (cast only)
__global__ void ln3_cast(const float* __restrict__ Q, const float* __restrict__ K,
                         const float* __restrict__ V,
                         u16* __restrict__ QN, u16* __restrict__ KN, u16* __restrict__ VB,
                         const float* __restrict__ g, const float* __restrict__ bb){
  __shared__ float red[8];
  const float* X; u16* Y; int doLN = 1;
  switch(blockIdx.y){
    case 0: X = Q; Y = QN; break;
    case 1: X = K; Y = KN; break;
    default: X = V; Y = VB; doLN = 0; break;
  }
  ln_core(X, Y, nullptr, g, bb, doLN, blockIdx.x, threadIdx.x, red);
}

__global__ void ln_post(const float* __restrict__ X, u16* __restrict__ Y,
                        float* __restrict__ Yf,
                        const float* __restrict__ g, const float* __restrict__ bb){
  __shared__ float red[8];
  ln_core(X, Y, Yf, g, bb, 1, blockIdx.x, threadIdx.x, red);
}

// ---------------- bf16 GEMM core, B^T layout ------------------------------
// C[m][n] = sum_k A[m][k]*Bt[n][k]; 128x128 tile, 4 waves 2x2 of 64x64, BK=64.
// MODE 0: write bf16 C*oscale.  MODE 1: out = Resid + gelu_exact(C), fp32.
template<int MODE>
__device__ __forceinline__ void gemm_core(
  const u16* __restrict__ A, const u16* __restrict__ Bt,
  u16* __restrict__ Obf, float* __restrict__ Of32, const float* __restrict__ Resid,
  int m0, int n0, int ldC, float oscale, u16* as, u16* bs)
{
  const int K = 1024;
  int t = threadIdx.x;
  int wave = t >> 6, lane = t & 63, quad = lane >> 4, l16 = lane & 15;
  int wm = (wave >> 1) * 64, wn = (wave & 1) * 64;
  int srow = t >> 3;              // wave*8 + lane/8
  f32x4 acc[4][4] = {};
  for(int k0 = 0; k0 < K; k0 += 64){
    __syncthreads();              // all waves done reading previous tile
    for(int p = 0; p < 4; p++){
      int r = p*32 + srow;
      int c = (t & 7) ^ (r & 7);
      glds16(A  + (size_t)(m0 + r) * K + k0 + c*8, as + p*2048 + wave*512);
      glds16(Bt + (size_t)(n0 + r) * K + k0 + c*8, bs + p*2048 + wave*512);
    }
    __syncthreads();              // drains vmcnt: tile staged
    bf16x8 af[2][4], bfr[2][4];
    for(int kk = 0; kk < 2; kk++)
      for(int mt = 0; mt < 4; mt++){
        int ra = wm + mt*16 + l16;
        af[kk][mt]  = ld8(&as[ra*64 + (((kk*4 + quad) ^ (ra & 7)) * 8)]);
        int rb = wn + mt*16 + l16;
        bfr[kk][mt] = ld8(&bs[rb*64 + (((kk*4 + quad) ^ (rb & 7)) * 8)]);
      }
    for(int kk = 0; kk < 2; kk++)
      for(int mt = 0; mt < 4; mt++)
        for(int nt = 0; nt < 4; nt++)
          acc[mt][nt] = __builtin_amdgcn_mfma_f32_16x16x32_bf16(af[kk][mt], bfr[kk][nt], acc[mt][nt], 0, 0, 0);
  }
  for(int mt = 0; mt < 4; mt++)
    for(int nt = 0; nt < 4; nt++){
      int col = n0 + wn + nt*16 + l16;
      for(int r = 0; r < 4; r++){
        int row = m0 + wm + mt*16 + quad*4 + r;
        size_t idx = (size_t)row * ldC + col;
        float v = acc[mt][nt][r];
        if(MODE == 0){
          Obf[idx] = f2bf(v * oscale);
        } else {
          float ge = 0.5f * v * (1.0f + erff(v * 0.70710678118f));
          Of32[idx] = Resid[idx] + ge;
        }
      }
    }
}

// fused Q/K/V projections: 1536 blocks.
// XCD-chunked remap (bijective: bx = 8t+c -> w = t + 192c): each XCD gets 192
// contiguous work items ordered (z, m, n) with n fastest, so the 8 n-tiles
// sharing one 256KB A-panel colocate on a single XCD's L2.
__global__ __launch_bounds__(256,3) void qkv_gemm(
  const u16* __restrict__ QN, const u16* __restrict__ KN, const u16* __restrict__ VB,
  const u16* __restrict__ WTq, const u16* __restrict__ WTk, const u16* __restrict__ WTv,
  u16* __restrict__ QP, u16* __restrict__ KP, u16* __restrict__ VT, float qscale)
{
  __shared__ u16 as[128*64];
  __shared__ u16 bs[128*64];
  int bx = blockIdx.x;
  int w = (bx >> 3) + 192 * (bx & 7);   // XCD-chunked work index, [0,1536)
  int z = w / 512, id = w - z * 512;    // id in [0,512): m = id>>3, n = id&7
  if(z == 0){
    gemm_core<0>(QN, WTq, QP, nullptr, nullptr, (id >> 3)*128, (id & 7)*128, 1024, qscale, as, bs);
  } else if(z == 1){
    gemm_core<0>(KN, WTk, KP, nullptr, nullptr, (id >> 3)*128, (id & 7)*128, 1024, 1.0f, as, bs);
  } else {
    gemm_core<0>(WTv, VB, VT, nullptr, nullptr, (id & 7)*128, (id >> 3)*128, 8192, 1.0f, as, bs);
  }
}

// final: Out = OLN + gelu(OLNb x WTo)
__global__ __launch_bounds__(256,3) void out_gemm(
  const u16* __restrict__ A, const u16* __restrict__ Bt,
  float* __restrict__ Of32, const float* __restrict__ Resid)
{
  __shared__ u16 as[128*64];
  __shared__ u16 bs[128*64];
  gemm_core<1>(A, Bt, nullptr, Of32, Resid, blockIdx.x*128, blockIdx.y*128, 1024, 1.0f, as, bs);
}

// ---------------- flash attention: 128 q-rows/block, Tk=64, HD=128 ---------
// R6: identical structure to R5 (wave-pairing: waves w and w+4 share 32
// q-rows, each handles a 32-token half; dbuf ks/vts; 1 barrier/step; pair
// reduction epilogue in LDS). ONE change: __launch_bounds__(512,4) ->
// (512,2). R5's counters showed VGPR_Count=64 with WRITE_SIZE 3.5x and
// hbm_bytes 3x = the compiler capped at 64 VGPRs (bound read as 32 waves/CU
// residency) and spilled ~60 registers into the 32-iter hot loop. LDS
// (80KB/block) already limits occupancy to 2 blocks/CU, so the correct cap
// is 128 VGPRs: demand ~130 now fits (at most a couple of cold spills).
__global__ __launch_bounds__(512,2) void flash_k(
  const u16* __restrict__ Qp, const u16* __restrict__ Kp, const u16* __restrict__ VT,
  float* __restrict__ Oout)
{
  __shared__ __align__(16) u16 smem[40960];   // 80 KB total
  u16* ks  = smem;            // [2][64][128] dbuf: chunk c at c^(row&15)
  u16* vts = smem + 16384;    // [2][128][64] dbuf: chunk c at c^(row&7)
  u16* ps  = smem + 32768;    // [128][64]: chunk c at c^(row&7)
  int t = threadIdx.x, wave = t >> 6, lane = t & 63, quad = lane >> 4, l16 = lane & 15;
  int l = blockIdx.x;            // 512 blocks
  int xcd = l & 7, i = l >> 3;   // i in 0..63
  int bh = xcd + 8 * (i & 3);    // 4 heads per XCD -> 4MB L2 working set
  int qt = i >> 2;               // 0..15 (128-row q tiles)
  int b = bh >> 3, h = bh & 7;
  size_t rowbase = (size_t)b * 2048;
  int colbase = h * 128;
  int wq = (wave & 3) * 32;      // this wave's q-row offset (2 m-tiles)
  int kb = (wave >> 2) * 32;     // this wave's token half within the 64-tile
  int khq = (kb >> 3) + quad;    // chunk index for pa/vts reads (khalf*4+quad)

  // Q fragments to registers: 32 wave-private rows, 2 m-tiles
  bf16x8 aq[2][4];
  for(int m = 0; m < 2; m++){
    const u16* qrow = Qp + (rowbase + qt*128 + wq + m*16 + l16) * 1024 + colbase + quad*8;
    for(int kk = 0; kk < 4; kk++) aq[m][kk] = ld8(qrow + kk*32);
  }

  float l_i[2][4] = {};          // per-lane, per-khalf partial denominators
  f32x4 oacc[2][8] = {};         // per-khalf partial O

  int krow = t >> 4;             // 0..31
  int kchunk = t & 15;
  int vrow = t >> 3;             // 0..63
  int vchunk = t & 7;

  // per-lane global source pointers; advance by constants each staged step.
  // second half-tile is a constant offset: K +32 rows (=32768 u16, same xor
  // since (32+krow)&15==krow&15); V +64 rows (=524288 u16, (64+vrow)&7 same).
  const u16* kp = Kp + (rowbase + krow) * 1024 + colbase + (kchunk ^ (krow & 15)) * 8;
  const u16* vt = VT + (size_t)(colbase + vrow) * 8192 + rowbase + (vchunk ^ (vrow & 7)) * 8;

  // prologue: stage tile 0 into buf 0
  {
    u16* kd = ks + wave*512;
    u16* vd = vts + wave*512;
    glds16(kp, kd);          glds16(kp + 32768, kd + 4096);
    glds16(vt, vd);          glds16(vt + 524288, vd + 4096);
    kp += 65536; vt += 64;
  }
  __syncthreads();               // vmcnt(0): tile 0 staged

  for(int kt = 0; kt < 2048; kt += 64){
    int buf = (kt >> 6) & 1;
    const u16* ksc = ks + buf*8192;
    const u16* vtc = vts + buf*8192;
    // stage next tile into buf^1 (readers retired by last barrier; drained
    // by this step's end barrier -> covered by the whole step's compute)
    if(kt + 64 < 2048){
      u16* kd = ks + (buf^1)*8192 + wave*512;
      u16* vd = vts + (buf^1)*8192 + wave*512;
      glds16(kp, kd);          glds16(kp + 32768, kd + 4096);
      glds16(vt, vd);          glds16(vt + 524288, vd + 4096);
      kp += 65536; vt += 64;
    }
    // ---- S = q k^T for this wave's 32 rows x 32 token-cols, ct-chunked to
    //      keep only 8 s-regs live (VGPR budget)
    for(int ct = 0; ct < 2; ct++){
      f32x4 s0 = {}, s1 = {};
      __builtin_amdgcn_s_setprio(1);
      for(int kk = 0; kk < 4; kk++){
        bf16x8 bb = ld8(&ksc[(kb + ct*16 + l16)*128 + (((kk*4 + quad) ^ l16) * 8)]);
        s0 = __builtin_amdgcn_mfma_f32_16x16x32_bf16(aq[0][kk], bb, s0, 0, 0, 0);
        s1 = __builtin_amdgcn_mfma_f32_16x16x32_bf16(aq[1][kk], bb, s1, 0, 0, 0);
      }
      __builtin_amdgcn_s_setprio(0);
      for(int r = 0; r < 4; r++){
        s0[r] = __builtin_amdgcn_exp2f(s0[r]);
        s1[r] = __builtin_amdgcn_exp2f(s1[r]);
      }
      int ch = (kb >> 3) + ct*2 + (l16 >> 3);   // source chunk of this col
      for(int r = 0; r < 4; r++){
        l_i[0][r] += s0[r];
        l_i[1][r] += s1[r];
        int pr0 = wq + quad*4 + r;              // m=0 row
        int pr1 = pr0 + 16;                     // m=1 row (same &7)
        int cx = (ch ^ (pr0 & 7)) * 8 + (l16 & 7);
        ps[pr0*64 + cx] = f2bf_fast(s0[r]);
        ps[pr1*64 + cx] = f2bf_fast(s1[r]);
      }
    }
    // ---- O += P V  (this wave's token half; frags shared across 2 m-tiles)
    bf16x8 pa0 = ld8(&ps[(wq + l16)*64      + ((khq ^ (l16 & 7)) * 8)]);
    bf16x8 pa1 = ld8(&ps[(wq + 16 + l16)*64 + ((khq ^ (l16 & 7)) * 8)]);
    __builtin_amdgcn_s_setprio(1);
    for(int dt = 0; dt < 8; dt++){
      bf16x8 bb = ld8(&vtc[(dt*16 + l16)*64 + ((khq ^ (l16 & 7)) * 8)]);
      oacc[0][dt] = __builtin_amdgcn_mfma_f32_16x16x32_bf16(pa0, bb, oacc[0][dt], 0, 0, 0);
      oacc[1][dt] = __builtin_amdgcn_mfma_f32_16x16x32_bf16(pa1, bb, oacc[1][dt], 0, 0, 0);
    }
    __builtin_amdgcn_s_setprio(0);
    // single barrier: drains this step's DMAs; retires all buf[cur] readers
    __syncthreads();
  }

  // ---- pair-reduction epilogue: khalf 0 publishes, khalf 1 adds & writes.
  // Reuses smem (all ks/vts/ps reads retired by the loop's final barrier).
  float* o_lds = (float*)smem;                 // [128][132] padded f32
  float* l_lds = (float*)(smem + 33792);       // byte 67584: [128][16] f32
  if(kb == 0){
    for(int m = 0; m < 2; m++)
      for(int r = 0; r < 4; r++){
        int row = wq + m*16 + quad*4 + r;
        l_lds[row*16 + l16] = l_i[m][r];
        for(int dt = 0; dt < 8; dt++)
          o_lds[row*132 + dt*16 + l16] = oacc[m][dt][r];
      }
  }
  __syncthreads();
  if(kb != 0){
    for(int m = 0; m < 2; m++){
      float rinv[4];
      for(int r = 0; r < 4; r++){
        int row = wq + m*16 + quad*4 + r;
        float lv = l_i[m][r] + l_lds[row*16 + l16];
        for(int o = 1; o < 16; o <<= 1) lv += __shfl_xor(lv, o, 64);
        rinv[r] = 1.f / lv;
      }
      for(int dt = 0; dt < 8; dt++){
        int col = colbase + dt*16 + l16;
        for(int r = 0; r < 4; r++){
          int row = wq + m*16 + quad*4 + r;
          size_t grow = rowbase + qt*128 + row;
          Oout[grow * 1024 + col] = (oacc[m][dt][r] + o_lds[row*132 + dt*16 + l16]) * rinv[r];
        }
      }
    }
  }
}

// ---------------------------------------------------------------------------
extern "C" void kernel_launch(void* const* d_in, const int* in_sizes, int n_in,
                              void* d_out, int out_size, void* d_ws, size_t ws_size,
                              hipStream_t stream){
  (void)in_sizes; (void)n_in; (void)out_size; (void)ws_size;
  const float* Q    = (const float*)d_in[0];
  const float* K    = (const float*)d_in[1];
  const float* V    = (const float*)d_in[2];
  const float* Wq   = (const float*)d_in[3];
  const float* Wk   = (const float*)d_in[4];
  const float* Wv   = (const float*)d_in[5];
  const float* Wo   = (const float*)d_in[6];
  const float* pre_g = (const float*)d_in[7];
  const float* pre_b = (const float*)d_in[8];
  const float* ln_g  = (const float*)d_in[9];
  const float* ln_b  = (const float*)d_in[10];
  float* Out = (float*)d_out;
  char* ws = (char*)d_ws;
  const size_t MB = 1024 * 1024;
  // ws layout (peak 104 MB):
  u16* WTq = (u16*)(ws + 0*MB);    // 2MB each, transposed bf16 weights
  u16* WTk = (u16*)(ws + 2*MB);
  u16* WTv = (u16*)(ws + 4*MB);
  u16* WTo = (u16*)(ws + 6*MB);
  u16* QN  = (u16*)(ws + 8*MB);    // 16MB each: LN'd/cast inputs
  u16* KN  = (u16*)(ws + 24*MB);
  u16* VB  = (u16*)(ws + 40*MB);
  u16* QP  = (u16*)(ws + 56*MB);   // 16MB each: projections
  u16* KP  = (u16*)(ws + 72*MB);
  u16* VT  = (u16*)(ws + 88*MB);   // 16MB: V projection TRANSPOSED [1024][8192]
  float* OLN  = (float*)(ws + 8*MB);   // 32MB, reuses QN/KN after flash
  u16*   OLNb = (u16*)(ws + 40*MB);    // 16MB, reuses VB

  const float qscale = 0.03125f * 1.44269504089f;  // 1/TEMP * log2(e)

  wcast_k<<<dim3(32,32,4), 256, 0, stream>>>(Wq,Wk,Wv,Wo, WTq,WTk,WTv,WTo);
  ln3_cast<<<dim3(8192,3), 256, 0, stream>>>(Q, K, V, QN, KN, VB, pre_g, pre_b);
  qkv_gemm<<<1536, 256, 0, stream>>>(QN, KN, VB, WTq, WTk, WTv, QP, KP, VT, qscale);
  flash_k<<<512, 512, 0, stream>>>(QP, KP, VT, Out);
  ln_post<<<8192, 256, 0, stream>>>(Out, OLNb, OLN, ln_g, ln_b);
  out_gemm<<<dim3(64,8), 256, 0, stream>>>(OLNb, WTo, Out, OLN);
}

// Round 7
// 331.375 us; speedup vs baseline: 1.2184x; 1.1029x over previous
//
#include <hip/hip_runtime.h>
#include <math.h>

typedef unsigned short u16;
typedef __bf16 bf16x8 __attribute__((ext_vector_type(8)));
typedef float f32x4 __attribute__((ext_vector_type(4)));

union B8u { uint4 u; bf16x8 v; u16 s[8]; };

__device__ __forceinline__ u16 f2bf(float f){
  unsigned u = __float_as_uint(f);
  u += 0x7fffu + ((u >> 16) & 1u);   // RNE
  return (u16)(u >> 16);
}
__device__ __forceinline__ bf16x8 ld8(const u16* p){
  B8u x; x.u = *(const uint4*)p; return x.v;
}
// async global->LDS, 16B per lane; lds base must be wave-uniform, lane i lands
// at lds + i*16 (m97/m104 semantics).
__device__ __forceinline__ void glds16(const u16* g, u16* l){
  __builtin_amdgcn_global_load_lds(
      (const __attribute__((address_space(1))) void*)g,
      (__attribute__((address_space(3))) void*)l, 16, 0, 0);
}

// ---------------- weight transpose-cast: W[k][n] fp32 -> Wt[n][k] bf16 -----
__global__ void wcast_k(const float* __restrict__ Wq, const float* __restrict__ Wk,
                        const float* __restrict__ Wv, const float* __restrict__ Wo,
                        u16* __restrict__ Tq, u16* __restrict__ Tk,
                        u16* __restrict__ Tv, u16* __restrict__ To){
  const float* W; u16* T;
  switch(blockIdx.z){
    case 0: W = Wq; T = Tq; break;
    case 1: W = Wk; T = Tk; break;
    case 2: W = Wv; T = Tv; break;
    default: W = Wo; T = To; break;
  }
  __shared__ u16 tile[32][33];
  int tx = threadIdx.x & 31, ty = threadIdx.x >> 5;   // 32 x 8
  int n0 = blockIdx.x * 32, k0 = blockIdx.y * 32;
  for(int i = ty; i < 32; i += 8)
    tile[i][tx] = f2bf(W[(size_t)(k0 + i) * 1024 + n0 + tx]);
  __syncthreads();
  for(int i = ty; i < 32; i += 8)
    T[(size_t)(n0 + i) * 1024 + k0 + tx] = tile[tx][i];
}

// ---------------- row LayerNorm (D=1024) + bf16 cast --------------------
__device__ __forceinline__ void ln_core(const float* __restrict__ X,
                                        u16* __restrict__ Y, float* __restrict__ Yf,
                                        const float* __restrict__ g,
                                        const float* __restrict__ bb,
                                        int doLN, int row, int t, float* red){
  float4 v = ((const float4*)(X + (size_t)row * 1024))[t];
  float o0 = v.x, o1 = v.y, o2 = v.z, o3 = v.w;
  if(doLN){
    float s  = o0 + o1 + o2 + o3;
    float ss = o0*o0 + o1*o1 + o2*o2 + o3*o3;
    for(int o = 32; o > 0; o >>= 1){
      s  += __shfl_down(s,  o, 64);
      ss += __shfl_down(ss, o, 64);
    }
    if((t & 63) == 0){ red[t >> 6] = s; red[4 + (t >> 6)] = ss; }
    __syncthreads();
    s  = red[0] + red[1] + red[2] + red[3];
    ss = red[4] + red[5] + red[6] + red[7];
    float mu  = s * (1.f/1024.f);
    float var = ss * (1.f/1024.f) - mu*mu;
    float rs  = rsqrtf(var + 1e-5f);
    float4 gg = ((const float4*)g)[t];
    float4 bv = ((const float4*)bb)[t];
    o0 = (o0 - mu) * rs * gg.x + bv.x;
    o1 = (o1 - mu) * rs * gg.y + bv.y;
    o2 = (o2 - mu) * rs * gg.z + bv.z;
    o3 = (o3 - mu) * rs * gg.w + bv.w;
  }
  if(Yf){
    float4 w; w.x=o0; w.y=o1; w.z=o2; w.w=o3;
    ((float4*)(Yf + (size_t)row * 1024))[t] = w;
  }
  ushort4 u;
  u.x = f2bf(o0); u.y = f2bf(o1); u.z = f2bf(o2); u.w = f2bf(o3);
  ((ushort4*)(Y + (size_t)row * 1024))[t] = u;
}

// fused: z=0 Q->QN (LN), z=1 K->KN (LN), z=2 V->VB (cast only)
__global__ void ln3_cast(const float* __restrict__ Q, const float* __restrict__ K,
                         const float* __restrict__ V,
                         u16* __restrict__ QN, u16* __restrict__ KN, u16* __restrict__ VB,
                         const float* __restrict__ g, const float* __restrict__ bb){
  __shared__ float red[8];
  const float* X; u16* Y; int doLN = 1;
  switch(blockIdx.y){
    case 0: X = Q; Y = QN; break;
    case 1: X = K; Y = KN; break;
    default: X = V; Y = VB; doLN = 0; break;
  }
  ln_core(X, Y, nullptr, g, bb, doLN, blockIdx.x, threadIdx.x, red);
}

__global__ void ln_post(const float* __restrict__ X, u16* __restrict__ Y,
                        float* __restrict__ Yf,
                        const float* __restrict__ g, const float* __restrict__ bb){
  __shared__ float red[8];
  ln_core(X, Y, Yf, g, bb, 1, blockIdx.x, threadIdx.x, red);
}

// ---------------- bf16 GEMM core, B^T layout ------------------------------
// C[m][n] = sum_k A[m][k]*Bt[n][k]; 128x128 tile, 4 waves 2x2 of 64x64, BK=64.
// MODE 0: write bf16 C*oscale.  MODE 1: out = Resid + gelu_exact(C), fp32.
template<int MODE>
__device__ __forceinline__ void gemm_core(
  const u16* __restrict__ A, const u16* __restrict__ Bt,
  u16* __restrict__ Obf, float* __restrict__ Of32, const float* __restrict__ Resid,
  int m0, int n0, int ldC, float oscale, u16* as, u16* bs)
{
  const int K = 1024;
  int t = threadIdx.x;
  int wave = t >> 6, lane = t & 63, quad = lane >> 4, l16 = lane & 15;
  int wm = (wave >> 1) * 64, wn = (wave & 1) * 64;
  int srow = t >> 3;              // wave*8 + lane/8
  f32x4 acc[4][4] = {};
  for(int k0 = 0; k0 < K; k0 += 64){
    __syncthreads();              // all waves done reading previous tile
    for(int p = 0; p < 4; p++){
      int r = p*32 + srow;
      int c = (t & 7) ^ (r & 7);
      glds16(A  + (size_t)(m0 + r) * K + k0 + c*8, as + p*2048 + wave*512);
      glds16(Bt + (size_t)(n0 + r) * K + k0 + c*8, bs + p*2048 + wave*512);
    }
    __syncthreads();              // drains vmcnt: tile staged
    bf16x8 af[2][4], bfr[2][4];
    for(int kk = 0; kk < 2; kk++)
      for(int mt = 0; mt < 4; mt++){
        int ra = wm + mt*16 + l16;
        af[kk][mt]  = ld8(&as[ra*64 + (((kk*4 + quad) ^ (ra & 7)) * 8)]);
        int rb = wn + mt*16 + l16;
        bfr[kk][mt] = ld8(&bs[rb*64 + (((kk*4 + quad) ^ (rb & 7)) * 8)]);
      }
    for(int kk = 0; kk < 2; kk++)
      for(int mt = 0; mt < 4; mt++)
        for(int nt = 0; nt < 4; nt++)
          acc[mt][nt] = __builtin_amdgcn_mfma_f32_16x16x32_bf16(af[kk][mt], bfr[kk][nt], acc[mt][nt], 0, 0, 0);
  }
  for(int mt = 0; mt < 4; mt++)
    for(int nt = 0; nt < 4; nt++){
      int col = n0 + wn + nt*16 + l16;
      for(int r = 0; r < 4; r++){
        int row = m0 + wm + mt*16 + quad*4 + r;
        size_t idx = (size_t)row * ldC + col;
        float v = acc[mt][nt][r];
        if(MODE == 0){
          Obf[idx] = f2bf(v * oscale);
        } else {
          // gelu exact via A&S 7.1.26 erf polynomial (max err 1.5e-7)
          float x  = v * 0.70710678118f;
          float ax = fabsf(x);
          float tt = 1.0f / (1.0f + 0.3275911f * ax);
          float poly = tt*(0.254829592f + tt*(-0.284496736f + tt*(1.421413741f
                     + tt*(-1.453152027f + tt*1.061405429f))));
          float er = 1.0f - poly * __expf(-ax*ax);
          er = (x < 0.0f) ? -er : er;
          float ge = 0.5f * v * (1.0f + er);
          Of32[idx] = Resid[idx] + ge;
        }
      }
    }
}

// fused Q/K/V projections: 1536 blocks.
// XCD-chunked remap (bijective: bx = 8t+c -> w = t + 192c): each XCD gets 192
// contiguous work items ordered (z, m, n) with n fastest, so the 8 n-tiles
// sharing one 256KB A-panel colocate on a single XCD's L2.
__global__ __launch_bounds__(256,3) void qkv_gemm(
  const u16* __restrict__ QN, const u16* __restrict__ KN, const u16* __restrict__ VB,
  const u16* __restrict__ WTq, const u16* __restrict__ WTk, const u16* __restrict__ WTv,
  u16* __restrict__ QP, u16* __restrict__ KP, u16* __restrict__ VT, float qscale)
{
  __shared__ u16 as[128*64];
  __shared__ u16 bs[128*64];
  int bx = blockIdx.x;
  int w = (bx >> 3) + 192 * (bx & 7);   // XCD-chunked work index, [0,1536)
  int z = w / 512, id = w - z * 512;    // id in [0,512): m = id>>3, n = id&7
  if(z == 0){
    gemm_core<0>(QN, WTq, QP, nullptr, nullptr, (id >> 3)*128, (id & 7)*128, 1024, qscale, as, bs);
  } else if(z == 1){
    gemm_core<0>(KN, WTk, KP, nullptr, nullptr, (id >> 3)*128, (id & 7)*128, 1024, 1.0f, as, bs);
  } else {
    gemm_core<0>(WTv, VB, VT, nullptr, nullptr, (id & 7)*128, (id >> 3)*128, 8192, 1.0f, as, bs);
  }
}

// final: Out = OLN + gelu(OLNb x WTo)
// NOTE: dim3(64,8) linearization already XCD-colocates the 8 n-tiles sharing
// an A-panel (64 % 8 == 0 -> same m => same XCD), so no remap needed here.
__global__ __launch_bounds__(256,3) void out_gemm(
  const u16* __restrict__ A, const u16* __restrict__ Bt,
  float* __restrict__ Of32, const float* __restrict__ Resid)
{
  __shared__ u16 as[128*64];
  __shared__ u16 bs[128*64];
  gemm_core<1>(A, Bt, nullptr, Of32, Resid, blockIdx.x*128, blockIdx.y*128, 1024, 1.0f, as, bs);
}

// ---------------- flash attention: 128 q-rows/block, Tk=64, HD=128 ---------
// R3 structure (best measured: 83.2 us): 8 waves x 16 q-rows (512 threads),
// single-buffered ks/vts, 2 barriers/iter with PIPELINED staging: K(t+1)
// issued after the barrier retiring ks readers, V(t+1) after the barrier
// retiring vts readers; each DMA drained by the vmcnt(0) of the NEXT barrier
// (one phase later), so latency is covered by compute. Wave-pairing (R5/R6)
// was tried and is conclusively slower (occupancy collapse); do not revisit.
__global__ __launch_bounds__(512,4) void flash_k(
  const u16* __restrict__ Qp, const u16* __restrict__ Kp, const u16* __restrict__ VT,
  float* __restrict__ Oout)
{
  __shared__ u16 ks[64*128];     // 16 KB: K rows, 16 chunks/row, chunk c at c^(row&15)
  __shared__ u16 vts[128*64];    // 16 KB: V^T rows, 8 chunks/row, chunk c at c^(row&7)
  __shared__ u16 ps[128][72];    // P round-trip (C-layout -> A-layout), padded
  int t = threadIdx.x, wave = t >> 6, lane = t & 63, quad = lane >> 4, l16 = lane & 15;
  int l = blockIdx.x;            // 512 blocks
  int xcd = l & 7, i = l >> 3;   // i in 0..63
  int bh = xcd + 8 * (i & 3);    // 4 heads per XCD -> 4MB L2 working set
  int qt = i >> 2;               // 0..15 (128-row q tiles)
  int b = bh >> 3, h = bh & 7;
  size_t rowbase = (size_t)b * 2048;
  int colbase = h * 128;
  int wq = wave * 16;            // this wave's q-row offset in tile (1 m-tile)

  // Q fragments directly to registers (wave-private 16 rows)
  bf16x8 aq[4];
  {
    const u16* qrow = Qp + (rowbase + qt*128 + wq + l16) * 1024 + colbase + quad*8;
    for(int kk = 0; kk < 4; kk++) aq[kk] = ld8(qrow + kk*32);
  }

  float l_i[4] = {};             // per-lane partial denominators
  f32x4 oacc[8] = {};

  int krow = t >> 4;             // 0..31
  int kchunk = lane & 15;        // == t & 15
  int vrow = t >> 3;             // 0..63
  int vchunk = lane & 7;         // == t & 7

  // prologue: stage tile 0 (K then V), drain, sync.
  // dest linear row check: (p*4096 + t*8)/128 = p*32 + t/16 == kr  (ks)
  //                        (p*4096 + t*8)/64  = p*64 + t/8  == vr  (vts)
  for(int p = 0; p < 2; p++){
    int kr = p*32 + krow;
    int ck = kchunk ^ (kr & 15);
    glds16(Kp + (rowbase + kr) * 1024 + colbase + ck*8, ks + p*4096 + wave*512);
  }
  for(int p = 0; p < 2; p++){
    int vr = p*64 + vrow;
    int cv = vchunk ^ (vr & 7);
    glds16(VT + (size_t)(colbase + vr) * 8192 + rowbase + cv*8,
           vts + p*4096 + wave*512);
  }
  __syncthreads();                     // vmcnt(0): tile 0 fully staged

  for(int kt = 0; kt < 2048; kt += 64){
    // ---- S = q k^T  (16 rows x 64 cols per wave)
    f32x4 s[4] = {};
    __builtin_amdgcn_s_setprio(1);
    for(int ct = 0; ct < 4; ct++)
      for(int kk = 0; kk < 4; kk++){
        bf16x8 bb = ld8(&ks[(ct*16 + l16)*128 + (((kk*4 + quad) ^ l16) * 8)]);
        s[ct] = __builtin_amdgcn_mfma_f32_16x16x32_bf16(aq[kk], bb, s[ct], 0, 0, 0);
      }
    __builtin_amdgcn_s_setprio(0);
    // ---- P = exp2(S); accumulate per-lane l; store P to LDS (round-half-up)
    for(int ct = 0; ct < 4; ct++)
      for(int r = 0; r < 4; r++)
        s[ct][r] = __builtin_amdgcn_exp2f(s[ct][r]);
    for(int r = 0; r < 4; r++){
      l_i[r] += (s[0][r] + s[1][r]) + (s[2][r] + s[3][r]);
      for(int ct = 0; ct < 4; ct++){
        unsigned u = __float_as_uint(s[ct][r]) + 0x8000u;
        ps[wq + quad*4 + r][ct*16 + l16] = (u16)(u >> 16);
      }
    }
    // barrier: drains V(kt) DMA (covered by QK+softmax above) and guarantees
    // every wave is done reading ks -> safe to overwrite ks next.
    __syncthreads();
    if(kt + 64 < 2048){
      for(int p = 0; p < 2; p++){
        int kr = p*32 + krow;
        int ck = kchunk ^ (kr & 15);
        glds16(Kp + (rowbase + kt + 64 + kr) * 1024 + colbase + ck*8,
               ks + p*4096 + wave*512);
      }
    }
    // ---- O += P V   (wave-private ps rows)
    bf16x8 pa0 = ld8(&ps[wq + l16][quad*8]);
    bf16x8 pa1 = ld8(&ps[wq + l16][32 + quad*8]);
    __builtin_amdgcn_s_setprio(1);
    for(int dt = 0; dt < 8; dt++){
      int vrw = (dt*16 + l16)*64;
      int r7 = l16 & 7;
      bf16x8 b0 = ld8(&vts[vrw + ((quad ^ r7) * 8)]);
      oacc[dt] = __builtin_amdgcn_mfma_f32_16x16x32_bf16(pa0, b0, oacc[dt], 0, 0, 0);
      bf16x8 b1 = ld8(&vts[vrw + (((4 + quad) ^ r7) * 8)]);
      oacc[dt] = __builtin_amdgcn_mfma_f32_16x16x32_bf16(pa1, b1, oacc[dt], 0, 0, 0);
    }
    __builtin_amdgcn_s_setprio(0);
    // barrier: drains K(kt+64) DMA (covered by PV above) and guarantees every
    // wave's vts reads are retired -> safe to overwrite vts next.
    __syncthreads();
    if(kt + 64 < 2048){
      for(int p = 0; p < 2; p++){
        int vr = p*64 + vrow;
        int cv = vchunk ^ (vr & 7);
        glds16(VT + (size_t)(colbase + vr) * 8192 + rowbase + kt + 64 + cv*8,
               vts + p*4096 + wave*512);
      }
    }
  }
  // reduce l across the 16 lanes holding each row (quad-local), then write O
  float rinv[4];
  for(int r = 0; r < 4; r++){
    float lv = l_i[r];
    for(int o = 1; o < 16; o <<= 1) lv += __shfl_xor(lv, o, 64);
    rinv[r] = 1.f / lv;
  }
  for(int dt = 0; dt < 8; dt++){
    int col = colbase + dt*16 + l16;
    for(int r = 0; r < 4; r++){
      size_t row = rowbase + qt*128 + wq + quad*4 + r;
      Oout[row * 1024 + col] = oacc[dt][r] * rinv[r];
    }
  }
}

// ---------------------------------------------------------------------------
extern "C" void kernel_launch(void* const* d_in, const int* in_sizes, int n_in,
                              void* d_out, int out_size, void* d_ws, size_t ws_size,
                              hipStream_t stream){
  (void)in_sizes; (void)n_in; (void)out_size; (void)ws_size;
  const float* Q    = (const float*)d_in[0];
  const float* K    = (const float*)d_in[1];
  const float* V    = (const float*)d_in[2];
  const float* Wq   = (const float*)d_in[3];
  const float* Wk   = (const float*)d_in[4];
  const float* Wv   = (const float*)d_in[5];
  const float* Wo   = (const float*)d_in[6];
  const float* pre_g = (const float*)d_in[7];
  const float* pre_b = (const float*)d_in[8];
  const float* ln_g  = (const float*)d_in[9];
  const float* ln_b  = (const float*)d_in[10];
  float* Out = (float*)d_out;
  char* ws = (char*)d_ws;
  const size_t MB = 1024 * 1024;
  // ws layout (peak 104 MB):
  u16* WTq = (u16*)(ws + 0*MB);    // 2MB each, transposed bf16 weights
  u16* WTk = (u16*)(ws + 2*MB);
  u16* WTv = (u16*)(ws + 4*MB);
  u16* WTo = (u16*)(ws + 6*MB);
  u16* QN  = (u16*)(ws + 8*MB);    // 16MB each: LN'd/cast inputs
  u16* KN  = (u16*)(ws + 24*MB);
  u16* VB  = (u16*)(ws + 40*MB);
  u16* QP  = (u16*)(ws + 56*MB);   // 16MB each: projections
  u16* KP  = (u16*)(ws + 72*MB);
  u16* VT  = (u16*)(ws + 88*MB);   // 16MB: V projection TRANSPOSED [1024][8192]
  float* OLN  = (float*)(ws + 8*MB);   // 32MB, reuses QN/KN after flash
  u16*   OLNb = (u16*)(ws + 40*MB);    // 16MB, reuses VB

  const float qscale = 0.03125f * 1.44269504089f;  // 1/TEMP * log2(e)

  wcast_k<<<dim3(32,32,4), 256, 0, stream>>>(Wq,Wk,Wv,Wo, WTq,WTk,WTv,WTo);
  ln3_cast<<<dim3(8192,3), 256, 0, stream>>>(Q, K, V, QN, KN, VB, pre_g, pre_b);
  qkv_gemm<<<1536, 256, 0, stream>>>(QN, KN, VB, WTq, WTk, WTv, QP, KP, VT, qscale);
  flash_k<<<512, 512, 0, stream>>>(QP, KP, VT, Out);
  ln_post<<<8192, 256, 0, stream>>>(Out, OLNb, OLN, ln_g, ln_b);
  out_gemm<<<dim3(64,8), 256, 0, stream>>>(OLNb, WTo, Out, OLN);
}